// Round 1
// baseline (189.775 us; speedup 1.0000x reference)
//
#include <hip/hip_runtime.h>

// Problem constants
#define EDIM 1024
#define SDIM 16
#define NBATCH 4
#define NSEQ 4096

// ws layout (in floats). [B][S][N] transposed layout for scan-friendly access.
#define OFF_BXT   0u            // Bx transposed   [4][16][4096]
#define OFF_DECT  262144u       // decay transposed
#define OFF_HSL   524288u       // h_local (scan with h0=0 per bigchunk)
#define OFF_PP    786432u       // prefix decay product within bigchunk
#define OFF_AGGP  1048576u      // per (chain, bigchunk) total decay product [64][4]
#define OFF_AGGH  1048832u      // per (chain, bigchunk) local final h      [64][4]
#define OFF_HINIT 1049088u      // per (chain, bigchunk) initial h          [64][4]

__device__ __forceinline__ void fma4(float4& a, float xv, const float4& b) {
    a.x = fmaf(xv, b.x, a.x);
    a.y = fmaf(xv, b.y, a.y);
    a.z = fmaf(xv, b.z, a.z);
    a.w = fmaf(xv, b.w, a.w);
}

// ---------------------------------------------------------------------------
// Kernel 1: Bx = x @ B_in  -> write Bx and decay=exp(-exp(A)*softplus(Bx))
// transposed to [B][S][N].
// Grid: 256 blocks x 256 threads. Block handles 64 rows (b,n).
// lane (tid&63) = row, wave (tid>>6) = K-quarter (256 e each).
// x staged through LDS (pad 129 -> conflict-free column reads).
// ---------------------------------------------------------------------------
__global__ __launch_bounds__(256) void k1_bx(const float* __restrict__ x,
                                             const float* __restrict__ A,
                                             const float* __restrict__ Bin,
                                             float* __restrict__ ws) {
    __shared__ float xs[64 * 129];
    __shared__ float red[4 * 64 * 17];

    const int tid  = threadIdx.x;
    const int lane = tid & 63;
    const int w    = tid >> 6;
    const int g0   = blockIdx.x * 64;      // global row base (b*4096+n)
    const int b    = g0 >> 12;
    const int n0   = g0 & 4095;

    const float4* xf4 = (const float4*)x;  // 256 float4 per row
    const float4* Bf4 = (const float4*)Bin;

    float4 acc0 = make_float4(0.f, 0.f, 0.f, 0.f);
    float4 acc1 = acc0, acc2 = acc0, acc3 = acc0;

    // prefetch chunk 0 into regs
    float4 buf[8];
#pragma unroll
    for (int k = 0; k < 8; k++) {
        int f = tid + 256 * k;
        int r = f >> 5, rem = f & 31, wp = rem >> 3, j4 = rem & 7;
        buf[k] = xf4[(size_t)(g0 + r) * 256 + wp * 64 + 0 * 8 + j4];
    }

    for (int c = 0; c < 8; c++) {
        __syncthreads();  // previous chunk's compute (xs readers) done
#pragma unroll
        for (int k = 0; k < 8; k++) {
            int f = tid + 256 * k;
            int r = f >> 5, rem = f & 31, wp = rem >> 3, j4 = rem & 7;
            float* p = &xs[r * 129 + wp * 32 + j4 * 4];
            p[0] = buf[k].x; p[1] = buf[k].y; p[2] = buf[k].z; p[3] = buf[k].w;
        }
        __syncthreads();
        if (c < 7) {
#pragma unroll
            for (int k = 0; k < 8; k++) {
                int f = tid + 256 * k;
                int r = f >> 5, rem = f & 31, wp = rem >> 3, j4 = rem & 7;
                buf[k] = xf4[(size_t)(g0 + r) * 256 + wp * 64 + (c + 1) * 8 + j4];
            }
        }
        // compute: this wave's e-window = [w*256 + c*32, +32)
        const int ebase = w * 256 + c * 32;
#pragma unroll 8
        for (int j = 0; j < 32; j++) {
            float xv = xs[lane * 129 + w * 32 + j];
            int e = ebase + j;
            float4 b0 = Bf4[e * 4 + 0];
            float4 b1 = Bf4[e * 4 + 1];
            float4 b2 = Bf4[e * 4 + 2];
            float4 b3 = Bf4[e * 4 + 3];
            fma4(acc0, xv, b0);
            fma4(acc1, xv, b1);
            fma4(acc2, xv, b2);
            fma4(acc3, xv, b3);
        }
    }

    // cross-wave reduction via LDS (pad 17 -> conflict-free)
    {
        int rb = (w * 64 + lane) * 17;
        red[rb + 0]  = acc0.x; red[rb + 1]  = acc0.y; red[rb + 2]  = acc0.z; red[rb + 3]  = acc0.w;
        red[rb + 4]  = acc1.x; red[rb + 5]  = acc1.y; red[rb + 6]  = acc1.z; red[rb + 7]  = acc1.w;
        red[rb + 8]  = acc2.x; red[rb + 9]  = acc2.y; red[rb + 10] = acc2.z; red[rb + 11] = acc2.w;
        red[rb + 12] = acc3.x; red[rb + 13] = acc3.y; red[rb + 14] = acc3.z; red[rb + 15] = acc3.w;
    }
    __syncthreads();

    float* Bxt  = ws + OFF_BXT;
    float* dect = ws + OFF_DECT;
    const int l  = tid & 63;
    const int sg = tid >> 6;
#pragma unroll
    for (int k = 0; k < 4; k++) {
        int s = sg * 4 + k;
        float v = red[(0 * 64 + l) * 17 + s] + red[(1 * 64 + l) * 17 + s] +
                  red[(2 * 64 + l) * 17 + s] + red[(3 * 64 + l) * 17 + s];
        // softplus (stable) then decay
        float sp  = fmaxf(v, 0.f) + log1pf(expf(-fabsf(v)));
        float dec = expf(-expf(A[s]) * sp);
        size_t o = (size_t)(b * 16 + s) * 4096 + n0 + l;
        Bxt[o]  = v;
        dect[o] = dec;
    }
}

// ---------------------------------------------------------------------------
// Kernel 2: chunked linear-recurrence scan.
// Grid: 256 blocks = 64 chains (b,s) x 4 bigchunks of 1024 steps.
// 256 threads; each thread composes 4 steps, Hillis-Steele block scan of
// (P, h) pairs, then expansion writes h_local and prefix product Pp.
// ---------------------------------------------------------------------------
__global__ __launch_bounds__(256) void k2_scan(float* __restrict__ ws) {
    const int tid   = threadIdx.x;
    const int blk   = blockIdx.x;
    const int bc    = blk & 3;
    const int chain = blk >> 2;  // b*16+s

    const size_t f4idx = (size_t)chain * 1024 + bc * 256 + tid;
    const float4* Bx4 = (const float4*)(ws + OFF_BXT);
    const float4* de4 = (const float4*)(ws + OFF_DECT);
    float4 bx = Bx4[f4idx];
    float4 d  = de4[f4idx];

    // thread-local composition over 4 steps (from identity)
    float P = d.x * d.y * d.z * d.w;
    float h = 0.f;
    h = h * d.x + bx.x;
    h = h * d.y + bx.y;
    h = h * d.z + bx.z;
    h = h * d.w + bx.w;

    __shared__ float sP[256], sH[256];
    sP[tid] = P; sH[tid] = h;
    __syncthreads();
    for (int off = 1; off < 256; off <<= 1) {
        float pp = 1.f, hp = 0.f;
        bool act = (tid >= off);
        if (act) { pp = sP[tid - off]; hp = sH[tid - off]; }
        float p = sP[tid], hh = sH[tid];
        __syncthreads();
        if (act) { sP[tid] = pp * p; sH[tid] = fmaf(hp, p, hh); }
        __syncthreads();
    }
    float Pexc = 1.f, hexc = 0.f;
    if (tid > 0) { Pexc = sP[tid - 1]; hexc = sH[tid - 1]; }

    // expansion: inclusive h_local and prefix product within bigchunk
    float hr = hexc, Pr = Pexc;
    float4 hsl, pp4;
    hr = fmaf(hr, d.x, bx.x); Pr *= d.x; hsl.x = hr; pp4.x = Pr;
    hr = fmaf(hr, d.y, bx.y); Pr *= d.y; hsl.y = hr; pp4.y = Pr;
    hr = fmaf(hr, d.z, bx.z); Pr *= d.z; hsl.z = hr; pp4.z = Pr;
    hr = fmaf(hr, d.w, bx.w); Pr *= d.w; hsl.w = hr; pp4.w = Pr;

    float4* hsl4 = (float4*)(ws + OFF_HSL);
    float4* ppo  = (float4*)(ws + OFF_PP);
    hsl4[f4idx] = hsl;
    ppo[f4idx]  = pp4;

    if (tid == 255) {
        ws[OFF_AGGP + blk] = Pr;  // total decay product over bigchunk
        ws[OFF_AGGH + blk] = hr;  // final local h of bigchunk
    }
}

// Kernel 2b: serial combine across bigchunks -> initial h per bigchunk.
__global__ void k2_fix(float* __restrict__ ws) {
    int c = threadIdx.x;  // chain 0..63
    float hI = 0.f;
#pragma unroll
    for (int bc = 0; bc < 4; bc++) {
        ws[OFF_HINIT + c * 4 + bc] = hI;
        hI = fmaf(hI, ws[OFF_AGGP + c * 4 + bc], ws[OFF_AGGH + c * 4 + bc]);
    }
}

// ---------------------------------------------------------------------------
// Kernel 3: y[b,t,e] = sum_s h[b,t,s] * C[s,e] + x[b,t,e] * D[e]
// h = h_local + Pp * hInit.  Grid: 256 blocks = 4 batches x 64 t-tiles(64).
// Each thread owns 4 e (C column chunk in regs), loops 64 timesteps.
// ---------------------------------------------------------------------------
__global__ __launch_bounds__(256) void k3_out(const float* __restrict__ x,
                                              const float* __restrict__ C,
                                              const float* __restrict__ D,
                                              const float* __restrict__ ws,
                                              float* __restrict__ out) {
    __shared__ float hlds[64 * 17];
    const int tid = threadIdx.x;
    const int blk = blockIdx.x;
    const int tc  = blk & 63;
    const int b   = blk >> 6;
    const int t0  = tc * 64;
    const int bc  = t0 >> 10;

    const float4* C4 = (const float4*)C;  // [16][256] float4
    float4 creg[16];
#pragma unroll
    for (int s = 0; s < 16; s++) creg[s] = C4[s * 256 + tid];
    float4 dreg = ((const float4*)D)[tid];

    // phase 1: resolve h for the 64 timesteps into LDS
    {
        const int tt = tid & 63;
        const int sg = tid >> 6;
        const float* hsl = ws + OFF_HSL;
        const float* Pp  = ws + OFF_PP;
#pragma unroll
        for (int k = 0; k < 4; k++) {
            int s = sg * 4 + k;
            int chain = b * 16 + s;
            float hI = ws[OFF_HINIT + chain * 4 + bc];
            size_t o = (size_t)chain * 4096 + t0 + tt;
            hlds[tt * 17 + s] = fmaf(Pp[o], hI, hsl[o]);
        }
    }
    __syncthreads();

    const float4* x4 = (const float4*)x;
    float4* o4 = (float4*)out;
    const size_t rowbase = ((size_t)b * 4096 + t0) * 256;
#pragma unroll 4
    for (int tt = 0; tt < 64; tt++) {
        float4 xv = x4[rowbase + tt * 256 + tid];
        float4 y;
        y.x = xv.x * dreg.x;
        y.y = xv.y * dreg.y;
        y.z = xv.z * dreg.z;
        y.w = xv.w * dreg.w;
#pragma unroll
        for (int s = 0; s < 16; s++) {
            float h = hlds[tt * 17 + s];
            fma4(y, h, creg[s]);
        }
        o4[rowbase + tt * 256 + tid] = y;
    }
}

extern "C" void kernel_launch(void* const* d_in, const int* in_sizes, int n_in,
                              void* d_out, int out_size, void* d_ws, size_t ws_size,
                              hipStream_t stream) {
    const float* x   = (const float*)d_in[0];
    const float* A   = (const float*)d_in[1];
    const float* Bin = (const float*)d_in[2];
    const float* C   = (const float*)d_in[3];
    const float* D   = (const float*)d_in[4];
    float* out = (float*)d_out;
    float* ws  = (float*)d_ws;

    hipLaunchKernelGGL(k1_bx,   dim3(256), dim3(256), 0, stream, x, A, Bin, ws);
    hipLaunchKernelGGL(k2_scan, dim3(256), dim3(256), 0, stream, ws);
    hipLaunchKernelGGL(k2_fix,  dim3(1),   dim3(64),  0, stream, ws);
    hipLaunchKernelGGL(k3_out,  dim3(256), dim3(256), 0, stream, x, C, D, ws, out);
}